// Round 1
// baseline (167.504 us; speedup 1.0000x reference)
//
#include <hip/hip_runtime.h>
#include <hip/hip_bf16.h>

#define B_N 4096
#define D_K 1024

typedef short bf16x8 __attribute__((ext_vector_type(8)));
typedef float f32x4 __attribute__((ext_vector_type(4)));
typedef unsigned short ushort8_t __attribute__((ext_vector_type(8)));

// monotonic float<->uint encoding for integer atomicMin/Max on floats
__device__ __forceinline__ unsigned fenc(float f) {
    unsigned u = __float_as_uint(f);
    return (u & 0x80000000u) ? ~u : (u | 0x80000000u);
}
__device__ __forceinline__ float fdec(unsigned e) {
    unsigned u = (e & 0x80000000u) ? (e & 0x7fffffffu) : ~e;
    return __uint_as_float(u);
}

__global__ void init_k(unsigned* __restrict__ minp, unsigned* __restrict__ maxn,
                       float* __restrict__ ps, float* __restrict__ ns) {
    int i = blockIdx.x * 256 + threadIdx.x;
    if (i < B_N) {
        minp[i] = fenc(INFINITY);
        maxn[i] = fenc(-INFINITY);
        ps[i] = 0.0f;
        ns[i] = 0.0f;
    }
}

// one block per row: L2-normalize, store bf16
__global__ __launch_bounds__(256) void norm_k(const float* __restrict__ feats,
                                              __hip_bfloat16* __restrict__ fb) {
    int row = blockIdx.x;
    int t = threadIdx.x;
    float4 v = ((const float4*)(feats + (size_t)row * D_K))[t];
    float s = v.x * v.x + v.y * v.y + v.z * v.z + v.w * v.w;
    #pragma unroll
    for (int o = 32; o > 0; o >>= 1) s += __shfl_down(s, o);
    __shared__ float red[4];
    if ((t & 63) == 0) red[t >> 6] = s;
    __syncthreads();
    float tot = red[0] + red[1] + red[2] + red[3];
    float inv = 1.0f / sqrtf(tot);
    __hip_bfloat16* dst = fb + (size_t)row * D_K + t * 4;
    dst[0] = __float2bfloat16(v.x * inv);
    dst[1] = __float2bfloat16(v.y * inv);
    dst[2] = __float2bfloat16(v.z * inv);
    dst[3] = __float2bfloat16(v.w * inv);
}

// PASS 1: per-row min over positives / max over negatives
// PASS 2: per-row selected exp-sums
template <int PASS>
__global__ __launch_bounds__(256) void gemm_k(const __hip_bfloat16* __restrict__ fb,
                                              const int* __restrict__ labels,
                                              unsigned* __restrict__ minp_u,
                                              unsigned* __restrict__ maxn_u,
                                              float* __restrict__ ps,
                                              float* __restrict__ ns) {
    __shared__ __align__(16) __hip_bfloat16 As[128 * 32];
    __shared__ __align__(16) __hip_bfloat16 Bs[128 * 32];
    __shared__ int labA[128], labB[128];

    int t = threadIdx.x;
    int row0 = blockIdx.y * 128;
    int col0 = blockIdx.x * 128;
    if (t < 128) {
        labA[t] = labels[row0 + t];
        labB[t] = labels[col0 + t];
    }

    int l = t & 63, w = t >> 6;
    int wrow = (w >> 1) * 64, wcol = (w & 1) * 64;
    int lr = l & 15, kg = l >> 4;

    f32x4 acc[4][4];
    #pragma unroll
    for (int i = 0; i < 4; i++)
        #pragma unroll
        for (int j = 0; j < 4; j++) acc[i][j] = (f32x4){0.f, 0.f, 0.f, 0.f};

    // staging: each thread moves 2x16B for A and 2x16B for B per K-step
    int sr = t >> 2;            // 0..63
    int sc = (t & 3) * 8;       // 0,8,16,24 (elements)
    const __hip_bfloat16* gA0 = fb + (size_t)(row0 + sr) * D_K + sc;
    const __hip_bfloat16* gA1 = fb + (size_t)(row0 + 64 + sr) * D_K + sc;
    const __hip_bfloat16* gB0 = fb + (size_t)(col0 + sr) * D_K + sc;
    const __hip_bfloat16* gB1 = fb + (size_t)(col0 + 64 + sr) * D_K + sc;
    __hip_bfloat16* lA0 = As + sr * 32 + sc;
    __hip_bfloat16* lA1 = As + (64 + sr) * 32 + sc;
    __hip_bfloat16* lB0 = Bs + sr * 32 + sc;
    __hip_bfloat16* lB1 = Bs + (64 + sr) * 32 + sc;

    for (int k0 = 0; k0 < D_K; k0 += 32) {
        *(ushort8_t*)lA0 = *(const ushort8_t*)(gA0 + k0);
        *(ushort8_t*)lA1 = *(const ushort8_t*)(gA1 + k0);
        *(ushort8_t*)lB0 = *(const ushort8_t*)(gB0 + k0);
        *(ushort8_t*)lB1 = *(const ushort8_t*)(gB1 + k0);
        __syncthreads();

        bf16x8 af[4], bfr[4];
        #pragma unroll
        for (int mi = 0; mi < 4; mi++)
            af[mi] = *(const bf16x8*)(As + (wrow + mi * 16 + lr) * 32 + kg * 8);
        #pragma unroll
        for (int ni = 0; ni < 4; ni++)
            bfr[ni] = *(const bf16x8*)(Bs + (wcol + ni * 16 + lr) * 32 + kg * 8);

        #pragma unroll
        for (int mi = 0; mi < 4; mi++)
            #pragma unroll
            for (int ni = 0; ni < 4; ni++)
                acc[mi][ni] = __builtin_amdgcn_mfma_f32_16x16x32_bf16(
                    af[mi], bfr[ni], acc[mi][ni], 0, 0, 0);
        __syncthreads();
    }

    // C/D mapping (verified m89/m91): col = lane&15, row = (lane>>4)*4 + reg
    if (PASS == 1) {
        #pragma unroll
        for (int mi = 0; mi < 4; mi++) {
            #pragma unroll
            for (int v = 0; v < 4; v++) {
                int rl = wrow + mi * 16 + kg * 4 + v;
                int myLab = labA[rl];
                float pmin = INFINITY, nmax = -INFINITY;
                #pragma unroll
                for (int ni = 0; ni < 4; ni++) {
                    float s = acc[mi][ni][v];
                    int cl = wcol + ni * 16 + lr;
                    if (labB[cl] == myLab) {
                        if (s < 1.0f - 1e-5f) pmin = fminf(pmin, s);
                    } else {
                        nmax = fmaxf(nmax, s);
                    }
                }
                #pragma unroll
                for (int m = 1; m < 16; m <<= 1) {
                    pmin = fminf(pmin, __shfl_xor(pmin, m));
                    nmax = fmaxf(nmax, __shfl_xor(nmax, m));
                }
                if (lr == 0) {
                    atomicMin(&minp_u[row0 + rl], fenc(pmin));
                    atomicMax(&maxn_u[row0 + rl], fenc(nmax));
                }
            }
        }
    } else {
        #pragma unroll
        for (int mi = 0; mi < 4; mi++) {
            #pragma unroll
            for (int v = 0; v < 4; v++) {
                int rl = wrow + mi * 16 + kg * 4 + v;
                int r = row0 + rl;
                int myLab = labA[rl];
                float minp = fdec(minp_u[r]);
                float maxn = fdec(maxn_u[r]);
                float psum = 0.0f, nsum = 0.0f;
                #pragma unroll
                for (int ni = 0; ni < 4; ni++) {
                    float s = acc[mi][ni][v];
                    int cl = wcol + ni * 16 + lr;
                    if (labB[cl] == myLab) {
                        if (s < 1.0f - 1e-5f && s - 0.1f < maxn)
                            psum += __expf(-2.0f * (s - 0.5f));
                    } else {
                        if (s + 0.1f > minp)
                            nsum += __expf(40.0f * (s - 0.5f));
                    }
                }
                #pragma unroll
                for (int m = 1; m < 16; m <<= 1) {
                    psum += __shfl_xor(psum, m);
                    nsum += __shfl_xor(nsum, m);
                }
                if (lr == 0) {
                    atomicAdd(&ps[r], psum);
                    atomicAdd(&ns[r], nsum);
                }
            }
        }
    }
}

__global__ __launch_bounds__(1024) void final_k(const float* __restrict__ ps,
                                                const float* __restrict__ ns,
                                                float* __restrict__ out) {
    int t = threadIdx.x;
    float sum = 0.0f;
    #pragma unroll
    for (int j = 0; j < 4; j++) {
        int r = t + j * 1024;
        float p = ps[r], n = ns[r];
        if (p > 0.0f && n > 0.0f)
            sum += log1pf(p) * 0.5f + log1pf(n) * 0.025f;  // 1/SCALE_POS, 1/SCALE_NEG
    }
    #pragma unroll
    for (int o = 32; o > 0; o >>= 1) sum += __shfl_down(sum, o);
    __shared__ float red[16];
    if ((t & 63) == 0) red[t >> 6] = sum;
    __syncthreads();
    if (t < 16) {
        float v = red[t];
        #pragma unroll
        for (int o = 8; o > 0; o >>= 1) v += __shfl_down(v, o, 16);
        if (t == 0) out[0] = v / (float)B_N;
    }
}

extern "C" void kernel_launch(void* const* d_in, const int* in_sizes, int n_in,
                              void* d_out, int out_size, void* d_ws, size_t ws_size,
                              hipStream_t stream) {
    const float* feats = (const float*)d_in[0];
    const int* labels = (const int*)d_in[1];
    float* out = (float*)d_out;

    char* ws = (char*)d_ws;
    __hip_bfloat16* fb = (__hip_bfloat16*)ws;               // 8 MB normalized bf16
    size_t off = (size_t)B_N * D_K * sizeof(__hip_bfloat16);
    unsigned* minp = (unsigned*)(ws + off); off += (size_t)B_N * 4;
    unsigned* maxn = (unsigned*)(ws + off); off += (size_t)B_N * 4;
    float* ps = (float*)(ws + off); off += (size_t)B_N * 4;
    float* ns = (float*)(ws + off);

    hipLaunchKernelGGL(init_k, dim3((B_N + 255) / 256), dim3(256), 0, stream,
                       minp, maxn, ps, ns);
    hipLaunchKernelGGL(norm_k, dim3(B_N), dim3(256), 0, stream, feats, fb);
    dim3 grid(32, 32);
    hipLaunchKernelGGL((gemm_k<1>), grid, dim3(256), 0, stream, fb, labels,
                       minp, maxn, ps, ns);
    hipLaunchKernelGGL((gemm_k<2>), grid, dim3(256), 0, stream, fb, labels,
                       minp, maxn, ps, ns);
    hipLaunchKernelGGL(final_k, dim3(1), dim3(1024), 0, stream, ps, ns, out);
}

// Round 2
// 106.398 us; speedup vs baseline: 1.5743x; 1.5743x over previous
//
#include <hip/hip_runtime.h>
#include <hip/hip_bf16.h>

#define B_N 4096
#define D_K 1024
#define NB 32   // 4096/128 tile-blocks per dim

typedef short bf16x8 __attribute__((ext_vector_type(8)));
typedef float f32x4 __attribute__((ext_vector_type(4)));

#define AS1 __attribute__((address_space(1)))
#define AS3 __attribute__((address_space(3)))

__device__ __forceinline__ void gload16(const void* g, void* l) {
    __builtin_amdgcn_global_load_lds((const AS1 void*)g, (AS3 void*)l, 16, 0, 0);
}

// monotonic float<->uint encoding for integer atomicMin/Max on floats
__device__ __forceinline__ unsigned fenc(float f) {
    unsigned u = __float_as_uint(f);
    return (u & 0x80000000u) ? ~u : (u | 0x80000000u);
}
__device__ __forceinline__ float fdec(unsigned e) {
    unsigned u = (e & 0x80000000u) ? (e & 0x7fffffffu) : ~e;
    return __uint_as_float(u);
}

__global__ void init_k(unsigned* __restrict__ minp, unsigned* __restrict__ maxn,
                       float* __restrict__ ps, float* __restrict__ ns) {
    int i = blockIdx.x * 256 + threadIdx.x;
    if (i < B_N) {
        minp[i] = fenc(INFINITY);
        maxn[i] = fenc(-INFINITY);
        ps[i] = 0.0f;
        ns[i] = 0.0f;
    }
}

// one block per row: L2-normalize, store bf16
__global__ __launch_bounds__(256) void norm_k(const float* __restrict__ feats,
                                              __hip_bfloat16* __restrict__ fb) {
    int row = blockIdx.x;
    int t = threadIdx.x;
    float4 v = ((const float4*)(feats + (size_t)row * D_K))[t];
    float s = v.x * v.x + v.y * v.y + v.z * v.z + v.w * v.w;
    #pragma unroll
    for (int o = 32; o > 0; o >>= 1) s += __shfl_down(s, o);
    __shared__ float red[4];
    if ((t & 63) == 0) red[t >> 6] = s;
    __syncthreads();
    float tot = red[0] + red[1] + red[2] + red[3];
    float inv = 1.0f / sqrtf(tot);
    __hip_bfloat16* dst = fb + (size_t)row * D_K + t * 4;
    dst[0] = __float2bfloat16(v.x * inv);
    dst[1] = __float2bfloat16(v.y * inv);
    dst[2] = __float2bfloat16(v.z * inv);
    dst[3] = __float2bfloat16(v.w * inv);
}

// Upper-triangular tile GEMM. PASS 1: min-pos/max-neg. PASS 2: selected exp-sums.
// Off-diagonal tiles update BOTH row-side (A rows) and col-side (B rows, via symmetry).
template <int PASS>
__global__ __launch_bounds__(256) void gemm_k(const __hip_bfloat16* __restrict__ fb,
                                              const int* __restrict__ labels,
                                              unsigned* __restrict__ minp_u,
                                              unsigned* __restrict__ maxn_u,
                                              float* __restrict__ ps,
                                              float* __restrict__ ns) {
    __shared__ __align__(16) __hip_bfloat16 As[128 * 32];
    __shared__ __align__(16) __hip_bfloat16 Bs[128 * 32];
    __shared__ int labA[128], labB[128];

    // triangular decode: blockIdx.x in [0, 528) -> (bi, bj), bi <= bj
    int n = blockIdx.x;
    int bi = 0;
    while (n >= NB - bi) { n -= NB - bi; bi++; }
    int bj = bi + n;
    bool diag = (bi == bj);
    int row0 = bi * 128, col0 = bj * 128;

    int t = threadIdx.x;
    if (t < 128) {
        labA[t] = labels[row0 + t];
        labB[t] = labels[col0 + t];
    }

    int l = t & 63, w = t >> 6;
    int wrow = (w >> 1) * 64, wcol = (w & 1) * 64;
    int lr = l & 15, kg = l >> 4;

    f32x4 acc[4][4];
    #pragma unroll
    for (int i = 0; i < 4; i++)
        #pragma unroll
        for (int j = 0; j < 4; j++) acc[i][j] = (f32x4){0.f, 0.f, 0.f, 0.f};

    // global_load_lds staging: wave w stages A rows [w*32, w*32+32) and B rows same,
    // as 2+2 chunks of 16 rows (1KB each: lane l -> row +(l>>2), col (l&3)*8 elems)
    int srow = l >> 2;
    int scol = (l & 3) * 8;
    const __hip_bfloat16* gA0 = fb + (size_t)(row0 + w * 32 + srow) * D_K + scol;
    const __hip_bfloat16* gA1 = gA0 + (size_t)16 * D_K;
    const __hip_bfloat16* gB0 = fb + (size_t)(col0 + w * 32 + srow) * D_K + scol;
    const __hip_bfloat16* gB1 = gB0 + (size_t)16 * D_K;
    __hip_bfloat16* lA = As + (w * 32) * 32;   // wave-uniform LDS base
    __hip_bfloat16* lB = Bs + (w * 32) * 32;

    for (int k0 = 0; k0 < D_K; k0 += 32) {
        gload16(gA0 + k0, lA);
        gload16(gA1 + k0, lA + 16 * 32);
        gload16(gB0 + k0, lB);
        gload16(gB1 + k0, lB + 16 * 32);
        __syncthreads();

        bf16x8 af[4], bfr[4];
        #pragma unroll
        for (int mi = 0; mi < 4; mi++)
            af[mi] = *(const bf16x8*)(As + (wrow + mi * 16 + lr) * 32 + kg * 8);
        #pragma unroll
        for (int ni = 0; ni < 4; ni++)
            bfr[ni] = *(const bf16x8*)(Bs + (wcol + ni * 16 + lr) * 32 + kg * 8);

        #pragma unroll
        for (int mi = 0; mi < 4; mi++)
            #pragma unroll
            for (int ni = 0; ni < 4; ni++)
                acc[mi][ni] = __builtin_amdgcn_mfma_f32_16x16x32_bf16(
                    af[mi], bfr[ni], acc[mi][ni], 0, 0, 0);
        __syncthreads();
    }

    // C/D mapping (verified m89/m91): col = lane&15 (lr), row = kg*4 + reg v
    if (PASS == 1) {
        // row-side: rows of A-block
        #pragma unroll
        for (int mi = 0; mi < 4; mi++) {
            #pragma unroll
            for (int v = 0; v < 4; v++) {
                int rl = wrow + mi * 16 + kg * 4 + v;
                int myLab = labA[rl];
                float pmin = INFINITY, nmax = -INFINITY;
                #pragma unroll
                for (int ni = 0; ni < 4; ni++) {
                    float s = acc[mi][ni][v];
                    int cl = wcol + ni * 16 + lr;
                    if (labB[cl] == myLab) {
                        if (s < 1.0f - 1e-5f) pmin = fminf(pmin, s);
                    } else {
                        nmax = fmaxf(nmax, s);
                    }
                }
                #pragma unroll
                for (int m = 1; m < 16; m <<= 1) {
                    pmin = fminf(pmin, __shfl_xor(pmin, m));
                    nmax = fmaxf(nmax, __shfl_xor(nmax, m));
                }
                if (lr == 0) {
                    atomicMin(&minp_u[row0 + rl], fenc(pmin));
                    atomicMax(&maxn_u[row0 + rl], fenc(nmax));
                }
            }
        }
        // col-side: rows of B-block via sim[c][r] = sim[r][c]
        if (!diag) {
            #pragma unroll
            for (int ni = 0; ni < 4; ni++) {
                int cl = wcol + ni * 16 + lr;
                int myLab = labB[cl];
                float pmin = INFINITY, nmax = -INFINITY;
                #pragma unroll
                for (int mi = 0; mi < 4; mi++) {
                    #pragma unroll
                    for (int v = 0; v < 4; v++) {
                        float s = acc[mi][ni][v];
                        int rl = wrow + mi * 16 + kg * 4 + v;
                        if (labA[rl] == myLab) {
                            if (s < 1.0f - 1e-5f) pmin = fminf(pmin, s);
                        } else {
                            nmax = fmaxf(nmax, s);
                        }
                    }
                }
                pmin = fminf(pmin, __shfl_xor(pmin, 16));
                pmin = fminf(pmin, __shfl_xor(pmin, 32));
                nmax = fmaxf(nmax, __shfl_xor(nmax, 16));
                nmax = fmaxf(nmax, __shfl_xor(nmax, 32));
                if (kg == 0) {
                    atomicMin(&minp_u[col0 + cl], fenc(pmin));
                    atomicMax(&maxn_u[col0 + cl], fenc(nmax));
                }
            }
        }
    } else {
        // row-side
        #pragma unroll
        for (int mi = 0; mi < 4; mi++) {
            #pragma unroll
            for (int v = 0; v < 4; v++) {
                int rl = wrow + mi * 16 + kg * 4 + v;
                int r = row0 + rl;
                int myLab = labA[rl];
                float minp = fdec(minp_u[r]);
                float maxn = fdec(maxn_u[r]);
                float psum = 0.0f, nsum = 0.0f;
                #pragma unroll
                for (int ni = 0; ni < 4; ni++) {
                    float s = acc[mi][ni][v];
                    int cl = wcol + ni * 16 + lr;
                    if (labB[cl] == myLab) {
                        if (s < 1.0f - 1e-5f && s - 0.1f < maxn)
                            psum += __expf(-2.0f * (s - 0.5f));
                    } else {
                        if (s + 0.1f > minp)
                            nsum += __expf(40.0f * (s - 0.5f));
                    }
                }
                #pragma unroll
                for (int m = 1; m < 16; m <<= 1) {
                    psum += __shfl_xor(psum, m);
                    nsum += __shfl_xor(nsum, m);
                }
                if (lr == 0) {
                    atomicAdd(&ps[r], psum);
                    atomicAdd(&ns[r], nsum);
                }
            }
        }
        // col-side
        if (!diag) {
            #pragma unroll
            for (int ni = 0; ni < 4; ni++) {
                int cl = wcol + ni * 16 + lr;
                int c = col0 + cl;
                int myLab = labB[cl];
                float minp = fdec(minp_u[c]);
                float maxn = fdec(maxn_u[c]);
                float psum = 0.0f, nsum = 0.0f;
                #pragma unroll
                for (int mi = 0; mi < 4; mi++) {
                    #pragma unroll
                    for (int v = 0; v < 4; v++) {
                        float s = acc[mi][ni][v];
                        int rl = wrow + mi * 16 + kg * 4 + v;
                        if (labA[rl] == myLab) {
                            if (s < 1.0f - 1e-5f && s - 0.1f < maxn)
                                psum += __expf(-2.0f * (s - 0.5f));
                        } else {
                            if (s + 0.1f > minp)
                                nsum += __expf(40.0f * (s - 0.5f));
                        }
                    }
                }
                psum += __shfl_xor(psum, 16);
                psum += __shfl_xor(psum, 32);
                nsum += __shfl_xor(nsum, 16);
                nsum += __shfl_xor(nsum, 32);
                if (kg == 0) {
                    atomicAdd(&ps[c], psum);
                    atomicAdd(&ns[c], nsum);
                }
            }
        }
    }
}

__global__ __launch_bounds__(1024) void final_k(const float* __restrict__ ps,
                                                const float* __restrict__ ns,
                                                float* __restrict__ out) {
    int t = threadIdx.x;
    float sum = 0.0f;
    #pragma unroll
    for (int j = 0; j < 4; j++) {
        int r = t + j * 1024;
        float p = ps[r], n = ns[r];
        if (p > 0.0f && n > 0.0f)
            sum += log1pf(p) * 0.5f + log1pf(n) * 0.025f;  // 1/SCALE_POS, 1/SCALE_NEG
    }
    #pragma unroll
    for (int o = 32; o > 0; o >>= 1) sum += __shfl_down(sum, o);
    __shared__ float red[16];
    if ((t & 63) == 0) red[t >> 6] = sum;
    __syncthreads();
    if (t < 16) {
        float v = red[t];
        #pragma unroll
        for (int o = 8; o > 0; o >>= 1) v += __shfl_down(v, o, 16);
        if (t == 0) out[0] = v / (float)B_N;
    }
}

extern "C" void kernel_launch(void* const* d_in, const int* in_sizes, int n_in,
                              void* d_out, int out_size, void* d_ws, size_t ws_size,
                              hipStream_t stream) {
    const float* feats = (const float*)d_in[0];
    const int* labels = (const int*)d_in[1];
    float* out = (float*)d_out;

    char* ws = (char*)d_ws;
    __hip_bfloat16* fb = (__hip_bfloat16*)ws;               // 8 MB normalized bf16
    size_t off = (size_t)B_N * D_K * sizeof(__hip_bfloat16);
    unsigned* minp = (unsigned*)(ws + off); off += (size_t)B_N * 4;
    unsigned* maxn = (unsigned*)(ws + off); off += (size_t)B_N * 4;
    float* ps = (float*)(ws + off); off += (size_t)B_N * 4;
    float* ns = (float*)(ws + off);

    hipLaunchKernelGGL(init_k, dim3((B_N + 255) / 256), dim3(256), 0, stream,
                       minp, maxn, ps, ns);
    hipLaunchKernelGGL(norm_k, dim3(B_N), dim3(256), 0, stream, feats, fb);
    int ntri = NB * (NB + 1) / 2;  // 528 upper-triangular tiles
    hipLaunchKernelGGL((gemm_k<1>), dim3(ntri), dim3(256), 0, stream, fb, labels,
                       minp, maxn, ps, ns);
    hipLaunchKernelGGL((gemm_k<2>), dim3(ntri), dim3(256), 0, stream, fb, labels,
                       minp, maxn, ps, ns);
    hipLaunchKernelGGL(final_k, dim3(1), dim3(1024), 0, stream, ps, ns, out);
}